// Round 11
// baseline (1172.462 us; speedup 1.0000x reference)
//
#include <hip/hip_runtime.h>
#include <hip/hip_bf16.h>

typedef float f32x4 __attribute__((ext_vector_type(4)));
typedef __bf16 bf16x8 __attribute__((ext_vector_type(8)));
typedef unsigned int u32;
typedef unsigned int u32x4 __attribute__((ext_vector_type(4)));

#if defined(__has_builtin)
#if __has_builtin(__builtin_amdgcn_exp2f)
#define EXP2F(x) __builtin_amdgcn_exp2f(x)
#else
#define EXP2F(x) exp2f(x)
#endif
#if __has_builtin(__builtin_amdgcn_rcpf)
#define RCPF(x) __builtin_amdgcn_rcpf(x)
#else
#define RCPF(x) (1.0f/(x))
#endif
#else
#define EXP2F(x) exp2f(x)
#define RCPF(x) (1.0f/(x))
#endif

#define MFMA16(a,b,c) __builtin_amdgcn_mfma_f32_16x16x32_bf16((a),(b),(c),0,0,0)

__device__ __forceinline__ unsigned short f2bf(float f) {
  return __builtin_bit_cast(unsigned short, (__bf16)f);
}

// pack two f32 -> one u32 of 2 bf16 (RNE), lo = a, hi = b
__device__ __forceinline__ u32 pkbf(float a, float b) {
  u32 d;
  asm("v_cvt_pk_bf16_f32 %0, %1, %2" : "=v"(d) : "v"(a), "v"(b));
  return d;
}

// d_ws layout: [0..65535] = W1Tg (pi x sigma permuted W1^T, fwd A image)
//              [65536..131071] = W1b (natural bf16 W1, bwd A image)
//   rho: jb=rho>>5, jf=(rho>>4)&1, a=(rho>>2)&3, c=rho&3  -> j = jb*32 + a*8 + jf*4 + c   [pi]
//   iota: kb=io>>5,  u=(io>>3)&3,  v=io&7                 -> i = kb*32 + (v>>2)*16 + u*4 + (v&3)  [sigma]
__global__ __launch_bounds__(256) void hn_prep(const float* __restrict__ W1,
                                               unsigned short* __restrict__ ws) {
  int t = blockIdx.x * 256 + threadIdx.x;  // 65536 threads
  int rho = t >> 7, io = t & 127;
  int j = (rho >> 5) * 32 + ((rho >> 2) & 3) * 8 + ((rho >> 4) & 1) * 4 + (rho & 3);
  int i = (io >> 5) * 32 + ((io >> 2) & 1) * 16 + ((io >> 3) & 3) * 4 + (io & 3);
  ws[t] = f2bf(W1[i * 512 + j]);          // W1Tg[rho][io]
  ws[65536 + t] = f2bf(W1[t]);            // W1b natural [i][j]
}

// 256-thr blocks (4 waves x 16 rows = 64 rows), 1024 blocks.
// __launch_bounds__(256,3): cap 170 regs -> 3 blocks/CU = 12 waves/CU =
// 3 waves/SIMD (the untried occupancy step). No weight LDS: both W1 images
// stream from L2 (256 KB, XCD-L2-resident). Persistent state 112 regs.
__global__ __launch_bounds__(256, 3) void hn_main(
    const float* __restrict__ x, const float* __restrict__ W1,
    const float* __restrict__ b1, const float* __restrict__ W2,
    const unsigned short* __restrict__ wsp, float* __restrict__ out) {
  __shared__ __align__(16) float b1s[512];  // b1 * 2*log2(e)
  __shared__ __align__(16) float w2s[512];

  const int tid = threadIdx.x;
  const int lane = tid & 63;
  const int w = tid >> 6;      // 0..3
  const int m = lane & 15;
  const int g = lane >> 4;

  b1s[tid] = b1[tid] * 2.8853900817779268f;
  b1s[tid + 256] = b1[tid + 256] * 2.8853900817779268f;
  w2s[tid] = W2[tid];
  w2s[tid + 256] = W2[tid + 256];
  __syncthreads();

  const int b0 = blockIdx.x * 64 + w * 16;

  // q/p f32 masters in sigma layout:
  // element r of frag = (row b0+m, i = 32kb + 16*(r>>2) + 4g + (r&3))
  float q[4][8], p[4][8];
#pragma unroll
  for (int kb = 0; kb < 4; ++kb) {
    const float* r0 = x + (long)(b0 + m) * 256 + kb * 32 + g * 4;
#pragma unroll
    for (int h = 0; h < 2; ++h) {
      f32x4 qv = *(const f32x4*)(r0 + h * 16);
      f32x4 pv = *(const f32x4*)(r0 + h * 16 + 128);
#pragma unroll
      for (int rr = 0; rr < 4; ++rr) {
        q[kb][4 * h + rr] = qv[rr];
        p[kb][4 * h + rr] = pv[rr];
      }
    }
  }

  // lane-constant byte bases into the two L2-resident weight images
  const char* aptr = (const char*)wsp + m * 256 + g * 16;            // fwd: row rho=..+m
  const char* bptr = (const char*)(wsp + 65536) + m * 1024 + g * 16; // bwd: row i=..+m

#pragma unroll 1
  for (int step = 0; step < 10; ++step) {
    // snapshot q_old as bf16; advance q with p_old (leapfrog: g uses q_old)
    u32x4 qbw[4];
#pragma unroll
    for (int kb = 0; kb < 4; ++kb)
#pragma unroll
      for (int h = 0; h < 4; ++h)
        qbw[kb][h] = pkbf(q[kb][2 * h], q[kb][2 * h + 1]);

#pragma unroll
    for (int kb = 0; kb < 4; ++kb)
#pragma unroll
      for (int r = 0; r < 8; ++r)
        q[kb][r] = fmaf(0.1f, p[kb][r], q[kb][r]);

    f32x4 gacc[8];  // C: col b = m, row i = 16nf + 4g + rr
#pragma unroll
    for (int nf = 0; nf < 8; ++nf) gacc[nf] = f32x4{0.f, 0.f, 0.f, 0.f};

#pragma unroll 1
    for (int jblk = 0; jblk < 16; ++jblk) {
      // ---- forward: z = W1Tg-tile * qbw (A from L2, B in regs)
      f32x4 z0 = f32x4{0.f, 0.f, 0.f, 0.f};
      f32x4 z1 = f32x4{0.f, 0.f, 0.f, 0.f};
#pragma unroll
      for (int kb = 0; kb < 4; ++kb) {
        bf16x8 qb = __builtin_bit_cast(bf16x8, qbw[kb]);
        bf16x8 a0 = *(const bf16x8*)(aptr + jblk * 8192 + kb * 64);
        bf16x8 a1 = *(const bf16x8*)(aptr + jblk * 8192 + 4096 + kb * 64);
        z0 = MFMA16(a0, qb, z0);
        z1 = MFMA16(a1, qb, z1);
      }
      // ---- act: s = W2[j]*sech^2(z+b1[j]); C-row (jf,rr) <-> j = 32jblk+8g+4jf+rr
      u32x4 sp;
#pragma unroll
      for (int jf = 0; jf < 2; ++jf) {
        f32x4 b1v = *(const f32x4*)(b1s + jblk * 32 + g * 8 + jf * 4);
        f32x4 w2v = *(const f32x4*)(w2s + jblk * 32 + g * 8 + jf * 4);
        const f32x4 zv = jf ? z1 : z0;
        float sv[4];
#pragma unroll
        for (int rr = 0; rr < 4; ++rr) {
          float zz = fmaf(zv[rr], 2.8853900817779268f, b1v[rr]);
          float e = EXP2F(zz);                 // e^(2(z+b1))
          float u = RCPF(e + 1.f);
          float th = fmaf(-2.f, u, 1.f);       // tanh
          sv[rr] = fmaf(-th * th, w2v[rr], w2v[rr]);
        }
        sp[jf * 2 + 0] = pkbf(sv[0], sv[1]);
        sp[jf * 2 + 1] = pkbf(sv[2], sv[3]);
      }
      bf16x8 sB = __builtin_bit_cast(bf16x8, sp);
      // ---- backward: gacc += W1b(A from L2) * s^T(B in regs)
#pragma unroll
      for (int nf = 0; nf < 8; ++nf) {
        bf16x8 af = *(const bf16x8*)(bptr + nf * 16384 + jblk * 64);
        gacc[nf] = MFMA16(af, sB, gacc[nf]);
      }
    }

    // p -= dt * g : gacc C-layout == p sigma-frag layout, static indices
#pragma unroll
    for (int kb = 0; kb < 4; ++kb)
#pragma unroll
      for (int r = 0; r < 8; ++r)
        p[kb][r] = fmaf(-0.1f, gacc[2 * kb + (r >> 2)][r & 3], p[kb][r]);

    __syncthreads();  // phase-lock block's 4 waves -> L1 reuse of weight slices
  }

  // ---- store concat(q, p) with the same sigma addressing
  float* orow = out + (long)(b0 + m) * 256;
#pragma unroll
  for (int kb = 0; kb < 4; ++kb) {
    float* o = orow + kb * 32 + g * 4;
#pragma unroll
    for (int h = 0; h < 2; ++h) {
      f32x4 qv, pv;
#pragma unroll
      for (int rr = 0; rr < 4; ++rr) {
        qv[rr] = q[kb][4 * h + rr];
        pv[rr] = p[kb][4 * h + rr];
      }
      *(f32x4*)(o + h * 16) = qv;
      *(f32x4*)(o + h * 16 + 128) = pv;
    }
  }
}

extern "C" void kernel_launch(void* const* d_in, const int* in_sizes, int n_in,
                              void* d_out, int out_size, void* d_ws, size_t ws_size,
                              hipStream_t stream) {
  const float* x  = (const float*)d_in[0];
  const float* W1 = (const float*)d_in[1];
  const float* b1 = (const float*)d_in[2];
  const float* W2 = (const float*)d_in[3];
  // d_in[4] = b2: affects only V's value, not its gradient -> unused.
  float* out = (float*)d_out;
  unsigned short* wsp = (unsigned short*)d_ws;  // 256 KB: W1Tg + W1b

  hipLaunchKernelGGL(hn_prep, dim3(256), dim3(256), 0, stream, W1, wsp);
  hipLaunchKernelGGL(hn_main, dim3(1024), dim3(256), 0, stream,
                     x, W1, b1, W2, wsp, out);
}